// Round 8
// baseline (47.609 us; speedup 1.0000x reference)
//
#include <hip/hip_runtime.h>

// Problem constants: B=8, N=2048, M=2048, D=128
#define B_DIM 8
#define N_DIM 2048
#define M_DIM 2048
#define D_DIM 128

typedef __bf16 bf16_t;
typedef bf16_t bf16x8 __attribute__((ext_vector_type(8)));
typedef float f32x4 __attribute__((ext_vector_type(4)));

#define GLOAD_LDS16(g, l)                                              \
    __builtin_amdgcn_global_load_lds(                                  \
        (const __attribute__((address_space(1))) void*)(g),            \
        (__attribute__((address_space(3))) void*)(l), 16, 0, 0)

// ---------------------------------------------------------------------------
// Kernel 1: fp32 -> bf16 (RNE) + row norms (from the SAME rounded values),
// written in the FRAGMENTED GRANULE layout:
//   16B granule index = grp*256 + gran*16 + r
//   grp = global_row/16, r = row&15, gran = 8-elem chunk (0..15)
// A wave MFMA fragment (gran = kk*4 + h, r = lane&15) is then a fully
// coalesced contiguous 1KB load, and a 128-row panel is 32KB linear for DMA.
// Thread (r = tid&15, gran = tid>>4) => ws write index = tid (linear).
// ---------------------------------------------------------------------------
__global__ __launch_bounds__(256) void prep_kernel(
    const float* __restrict__ L, const float* __restrict__ R,
    bf16x8* __restrict__ LbF, bf16x8* __restrict__ RbF,
    float* __restrict__ nL, float* __restrict__ nR)
{
    __shared__ float part[256];

    const int tid  = threadIdx.x;
    const int r    = tid & 15;
    const int gran = tid >> 4;
    const int grp  = blockIdx.x;              // [0, 1024)
    const int row  = grp * 16 + r;

    const float* src  = blockIdx.y ? R : L;
    bf16x8*      dstF = blockIdx.y ? RbF : LbF;
    float*       ndst = blockIdx.y ? nR : nL;

    float4 v0 = ((const float4*)src)[(size_t)row * 32 + gran * 2];
    float4 v1 = ((const float4*)src)[(size_t)row * 32 + gran * 2 + 1];
    bf16x8 p = { (bf16_t)v0.x, (bf16_t)v0.y, (bf16_t)v0.z, (bf16_t)v0.w,
                 (bf16_t)v1.x, (bf16_t)v1.y, (bf16_t)v1.z, (bf16_t)v1.w };
    dstF[(size_t)grp * 256 + tid] = p;

    float s = 0.0f;
    #pragma unroll
    for (int j = 0; j < 8; ++j) { float x = (float)p[j]; s = fmaf(x, x, s); }
    part[tid] = s;
    __syncthreads();
    if (tid < 16) {
        float t = 0.0f;
        #pragma unroll
        for (int k = 0; k < 16; ++k) t += part[k * 16 + tid];
        ndst[grp * 16 + tid] = t;
    }
}

// ---------------------------------------------------------------------------
// Kernel 2: minimal-state MFMA distance tile. One 128x128 tile per block:
//   - B tile: 8 global_load_lds DMAs (32KB linear, zero VALU / zero VGPR)
//   - A fragments: 16 contiguous 1KB loads straight into registers
//   - one __syncthreads (no stores in flight yet -> harmless vmcnt drain)
//   - 4 quarters: {4 ds_read -> 16 MFMA -> epilogue -> 4 float4 stores}
// Tail stores drain asynchronously after s_endpgm issue, overlapping the
// next block. ~33KB LDS + low VGPR => 4 blocks/CU (16 waves), 2048 short
// blocks => store traffic statistically smooth across the whole kernel.
// MFMA operands SWAPPED (mfma(B,A)): out-row = lane&15 (A-row),
// out-col = (lane>>4)*4 + reg (B-row) => contiguous float4 stores.
// ---------------------------------------------------------------------------
__global__ __launch_bounds__(256, 4) void dist_main_kernel(
    const bf16x8* __restrict__ LbF, const bf16x8* __restrict__ RbF,
    const float* __restrict__ nL, const float* __restrict__ nR,
    float* __restrict__ out)
{
    __shared__ bf16x8 Bls[2048];   // 32 KB

    const int tid  = threadIdx.x;
    const int bx   = blockIdx.x;   // M tile (B rows / out cols)
    const int by   = blockIdx.y;   // N tile (A rows / out rows)
    const int bz   = blockIdx.z;   // batch
    const int wid  = tid >> 6;
    const int lane = tid & 63;
    const int lr   = lane & 15;
    const int h    = lane >> 4;    // 0..3

    const int wM   = (wid >> 1) * 64;
    const int wN   = (wid & 1) * 64;
    const int bgrp = (wid & 1) * 4;    // B 16-row-group base within tile

    // ---- B tile: direct-to-LDS DMA, linear 32KB
    const bf16x8* bsrc = RbF + (size_t)(bz * 128 + bx * 8) * 256;
    char* BlsB = (char*)Bls;
    #pragma unroll
    for (int i = 0; i < 8; ++i) {
        const int chunk = wid * 8 + i;             // [0,32) 1KB chunks
        GLOAD_LDS16(bsrc + chunk * 64 + lane, BlsB + chunk * 1024);
    }

    // ---- A fragments + norms straight into registers
    const int gA0 = bz * 128 + by * 8 + (wid >> 1) * 4;
    bf16x8 af[4][4];
    #pragma unroll
    for (int kk = 0; kk < 4; ++kk) {
        const int gi = (kk * 4 + h) * 16 + lr;
        #pragma unroll
        for (int mt = 0; mt < 4; ++mt)
            af[mt][kk] = LbF[(size_t)(gA0 + mt) * 256 + gi];
    }
    float l2v[4];
    #pragma unroll
    for (int mt = 0; mt < 4; ++mt)
        l2v[mt] = nL[bz * N_DIM + by * 128 + wM + mt * 16 + lr];

    __syncthreads();   // DMA + af loads complete; no stores in flight yet

    const float* nRb = nR + bz * M_DIM + bx * 128;
    const size_t outBase =
        ((size_t)bz * N_DIM + (size_t)by * 128) * M_DIM + (size_t)bx * 128;

    #pragma unroll
    for (int q = 0; q < 4; ++q) {
        f32x4 acc[4] = {};
        #pragma unroll
        for (int kk = 0; kk < 4; ++kk) {
            const bf16x8 bfr = Bls[(bgrp + q) * 256 + (kk * 4 + h) * 16 + lr];
            #pragma unroll
            for (int mt = 0; mt < 4; ++mt)
                acc[mt] = __builtin_amdgcn_mfma_f32_16x16x32_bf16(
                    bfr, af[mt][kk], acc[mt], 0, 0, 0);
        }
        const int colb = wN + q * 16 + h * 4;
        const f32x4 r2v = *(const f32x4*)&nRb[colb];
        #pragma unroll
        for (int mt = 0; mt < 4; ++mt) {
            const int row_l = wM + mt * 16 + lr;
            const float l2 = l2v[mt];
            f32x4 a = acc[mt], o;
            #pragma unroll
            for (int e = 0; e < 4; ++e) {
                float d2 = fmaf(-2.0f, a[e], l2 + r2v[e]);
                d2 = fmaxf(d2, 0.0f);
                float sq = __builtin_amdgcn_sqrtf(d2);
                o[e] = __builtin_amdgcn_rcpf(1.0f + sq);
            }
            *(f32x4*)(out + outBase + (size_t)row_l * M_DIM + colb) = o;
        }
    }
}

// ---------------------------------------------------------------------------
// Fallback: R6 fused kernel (known-passing, 41.9us) in case ws is too small.
// ---------------------------------------------------------------------------
#define NT_TILES 4

__device__ __forceinline__ void lgkm_barrier() {
    asm volatile("s_waitcnt lgkmcnt(0)" ::: "memory");
    __builtin_amdgcn_s_barrier();
}

__global__ __launch_bounds__(256, 2) void fused_dist_fallback(
    const float* __restrict__ L, const float* __restrict__ R,
    float* __restrict__ out)
{
    __shared__ bf16x8 Als[2048];
    __shared__ bf16x8 Bls[2048];
    __shared__ float nAs[128];
    __shared__ float nBs[128];

    const int tid  = threadIdx.x;
    const int bxg  = blockIdx.x;
    const int by   = blockIdx.y;
    const int bz   = blockIdx.z;
    const int wid  = tid >> 6;
    const int lane = tid & 63;
    const int lr   = lane & 15;
    const int h    = lane >> 4;
    const int r    = tid >> 4;
    const int gran = tid & 15;

    const float* Asrc = L + ((size_t)bz * N_DIM + (size_t)by * 128) * D_DIM;
    const float* Rbat = R + (size_t)bz * M_DIM * D_DIM;

    #pragma unroll
    for (int i = 0; i < 8; ++i) {
        int row = i * 16 + r;
        float4 v0 = ((const float4*)Asrc)[(size_t)row * 32 + gran * 2];
        float4 v1 = ((const float4*)Asrc)[(size_t)row * 32 + gran * 2 + 1];
        bf16x8 p = { (bf16_t)v0.x, (bf16_t)v0.y, (bf16_t)v0.z, (bf16_t)v0.w,
                     (bf16_t)v1.x, (bf16_t)v1.y, (bf16_t)v1.z, (bf16_t)v1.w };
        Als[i * 256 + gran * 16 + (r ^ gran)] = p;
        float s = 0.0f;
        #pragma unroll
        for (int j = 0; j < 8; ++j) { float x = (float)p[j]; s = fmaf(x, x, s); }
        s += __shfl_xor(s, 1); s += __shfl_xor(s, 2);
        s += __shfl_xor(s, 4); s += __shfl_xor(s, 8);
        if (gran == 0) nAs[i * 16 + r] = s;
    }
    {
        const float* Bsrc = Rbat + (size_t)(bxg * NT_TILES) * 128 * D_DIM;
        #pragma unroll
        for (int i = 0; i < 8; ++i) {
            int row = i * 16 + r;
            float4 v0 = ((const float4*)Bsrc)[(size_t)row * 32 + gran * 2];
            float4 v1 = ((const float4*)Bsrc)[(size_t)row * 32 + gran * 2 + 1];
            bf16x8 p = { (bf16_t)v0.x, (bf16_t)v0.y, (bf16_t)v0.z, (bf16_t)v0.w,
                         (bf16_t)v1.x, (bf16_t)v1.y, (bf16_t)v1.z, (bf16_t)v1.w };
            Bls[i * 256 + gran * 16 + (r ^ gran)] = p;
            float s = 0.0f;
            #pragma unroll
            for (int j = 0; j < 8; ++j) { float x = (float)p[j]; s = fmaf(x, x, s); }
            s += __shfl_xor(s, 1); s += __shfl_xor(s, 2);
            s += __shfl_xor(s, 4); s += __shfl_xor(s, 8);
            if (gran == 0) nBs[i * 16 + r] = s;
        }
    }
    lgkm_barrier();

    const int wM = (wid >> 1) * 64;
    const int wN = (wid & 1) * 64;
    const int agrp = (wid >> 1) * 4;
    const int bgrp = (wid & 1) * 4;

    bf16x8 af[4][4];
    #pragma unroll
    for (int kk = 0; kk < 4; ++kk) {
        int gr = kk * 4 + h;
        int gi = gr * 16 + (lr ^ gr);
        #pragma unroll
        for (int mt = 0; mt < 4; ++mt)
            af[mt][kk] = Als[(agrp + mt) * 256 + gi];
    }
    float l2v[4];
    #pragma unroll
    for (int mt = 0; mt < 4; ++mt) l2v[mt] = nAs[wM + mt * 16 + lr];

    for (int t = 0; t < NT_TILES; ++t) {
        const int bx = bxg * NT_TILES + t;

        f32x4 acc[4][4] = {};
        #pragma unroll
        for (int kk = 0; kk < 4; ++kk) {
            int gr = kk * 4 + h;
            int gi = gr * 16 + (lr ^ gr);
            bf16x8 bfr[4];
            #pragma unroll
            for (int q = 0; q < 4; ++q)
                bfr[q] = Bls[(bgrp + q) * 256 + gi];
            #pragma unroll
            for (int mt = 0; mt < 4; ++mt)
                #pragma unroll
                for (int q = 0; q < 4; ++q)
                    acc[mt][q] = __builtin_amdgcn_mfma_f32_16x16x32_bf16(
                        bfr[q], af[mt][kk], acc[mt][q], 0, 0, 0);
        }

        float4 pf0[8], pf1[8];
        if (t + 1 < NT_TILES) {
            const float* Bsrc = Rbat + (size_t)(bx + 1) * 128 * D_DIM;
            #pragma unroll
            for (int i = 0; i < 8; ++i) {
                int row = i * 16 + r;
                pf0[i] = ((const float4*)Bsrc)[(size_t)row * 32 + gran * 2];
                pf1[i] = ((const float4*)Bsrc)[(size_t)row * 32 + gran * 2 + 1];
            }
        }

        f32x4 r2v[4];
        #pragma unroll
        for (int q = 0; q < 4; ++q)
            r2v[q] = *(const f32x4*)&nBs[wN + q * 16 + h * 4];
        const size_t outBase =
            ((size_t)bz * N_DIM + (size_t)by * 128) * M_DIM + (size_t)bx * 128;
        #pragma unroll
        for (int mt = 0; mt < 4; ++mt) {
            const int row_l = wM + mt * 16 + lr;
            const float l2 = l2v[mt];
            float* orow = out + outBase + (size_t)row_l * M_DIM;
            #pragma unroll
            for (int q = 0; q < 4; ++q) {
                f32x4 a = acc[mt][q];
                f32x4 o;
                #pragma unroll
                for (int e = 0; e < 4; ++e) {
                    float d2 = fmaf(-2.0f, a[e], l2 + r2v[q][e]);
                    d2 = fmaxf(d2, 0.0f);
                    float sq = __builtin_amdgcn_sqrtf(d2);
                    o[e] = __builtin_amdgcn_rcpf(1.0f + sq);
                }
                *(f32x4*)(orow + wN + q * 16 + h * 4) = o;
            }
        }

        if (t + 1 < NT_TILES) {
            lgkm_barrier();
            #pragma unroll
            for (int i = 0; i < 8; ++i) {
                bf16x8 p = { (bf16_t)pf0[i].x, (bf16_t)pf0[i].y,
                             (bf16_t)pf0[i].z, (bf16_t)pf0[i].w,
                             (bf16_t)pf1[i].x, (bf16_t)pf1[i].y,
                             (bf16_t)pf1[i].z, (bf16_t)pf1[i].w };
                Bls[i * 256 + gran * 16 + (r ^ gran)] = p;
                float s = 0.0f;
                #pragma unroll
                for (int j = 0; j < 8; ++j) { float x = (float)p[j]; s = fmaf(x, x, s); }
                s += __shfl_xor(s, 1); s += __shfl_xor(s, 2);
                s += __shfl_xor(s, 4); s += __shfl_xor(s, 8);
                if (gran == 0) nBs[i * 16 + r] = s;
            }
            lgkm_barrier();
        }
    }
}

extern "C" void kernel_launch(void* const* d_in, const int* in_sizes, int n_in,
                              void* d_out, int out_size, void* d_ws, size_t ws_size,
                              hipStream_t stream) {
    const float* L = (const float*)d_in[0];
    const float* R = (const float*)d_in[1];
    float* out = (float*)d_out;

    const size_t LB_BYTES = (size_t)B_DIM * N_DIM * D_DIM * 2;  // 4 MiB
    const size_t NL_BYTES = (size_t)B_DIM * N_DIM * 4;          // 64 KiB
    const size_t need = 2 * LB_BYTES + 2 * NL_BYTES;

    if (ws_size >= need) {
        char* ws = (char*)d_ws;
        bf16x8* LbF = (bf16x8*)ws;
        bf16x8* RbF = (bf16x8*)(ws + LB_BYTES);
        float*  nLp = (float*)(ws + 2 * LB_BYTES);
        float*  nRp = (float*)(ws + 2 * LB_BYTES + NL_BYTES);

        prep_kernel<<<dim3(1024, 2, 1), dim3(256), 0, stream>>>(L, R, LbF, RbF, nLp, nRp);
        dist_main_kernel<<<dim3(M_DIM / 128, N_DIM / 128, B_DIM), dim3(256), 0, stream>>>(
            LbF, RbF, nLp, nRp, out);
    } else {
        fused_dist_fallback<<<dim3(M_DIM / (128 * NT_TILES), N_DIM / 128, B_DIM),
                              dim3(256), 0, stream>>>(L, R, out);
    }
}